// Round 1
// baseline (907.262 us; speedup 1.0000x reference)
//
#include <hip/hip_runtime.h>
#include <hip/hip_bf16.h>

// CCNet unit: conv3x3(2048->512)+BN+ReLU, 2x criss-cross attention, conv3x3(512->512)+BN+ReLU
// All GEMM-shaped compute via mfma_f32_16x16x32_bf16; f32 accumulate; f32 softmax.
// Requires ws_size >= ~193.2 MB.

typedef __bf16 bf16;
typedef __bf16 bf16x8 __attribute__((ext_vector_type(8)));
typedef float f32x4 __attribute__((ext_vector_type(4)));

#define DEVFN static __device__ __forceinline__

DEVFN void gload16(const void* g, void* l) {
  __builtin_amdgcn_global_load_lds((const __attribute__((address_space(1))) void*)g,
                                   (__attribute__((address_space(3))) void*)l,
                                   16, 0, 0);
}
DEVFN void vmwait() { asm volatile("s_waitcnt vmcnt(0)" ::: "memory"); }

DEVFN f32x4 mfma16(bf16x8 a, bf16x8 b, f32x4 c) {
  return __builtin_amdgcn_mfma_f32_16x16x32_bf16(a, b, c, 0, 0, 0);
}

// ---------------------------------------------------------------- prep kernels

// dst[tap][n][k] = src[n][k][tap] (bf16 cast). total = 512*Kc.
__global__ void prep_w(const float* __restrict__ src, bf16* __restrict__ dst, int total) {
  int nk = blockIdx.x * 256 + threadIdx.x;
  if (nk < total) {
#pragma unroll
    for (int t = 0; t < 9; ++t)
      dst[(size_t)t * total + nk] = (bf16)src[(size_t)nk * 9 + t];
  }
}

__global__ void prep_misc(const float* __restrict__ qw, const float* __restrict__ kw,
                          const float* __restrict__ vw, const float* __restrict__ qb,
                          const float* __restrict__ kb, const float* __restrict__ vb,
                          const float* __restrict__ g1, const float* __restrict__ b1,
                          const float* __restrict__ m1, const float* __restrict__ v1,
                          const float* __restrict__ g2, const float* __restrict__ b2,
                          const float* __restrict__ m2, const float* __restrict__ v2,
                          bf16* __restrict__ wqkv, float* __restrict__ qkvb,
                          float* __restrict__ sc1, float* __restrict__ bi1,
                          float* __restrict__ sc2, float* __restrict__ bi2) {
  int o = blockIdx.x * 256 + threadIdx.x;
  if (o < 640 * 512) {
    int n = o >> 9, k2 = o & 511;
    float v = (n < 64) ? qw[n * 512 + k2]
            : (n < 128) ? kw[(n - 64) * 512 + k2]
                        : vw[(n - 128) * 512 + k2];
    wqkv[o] = (bf16)v;
  }
  if (o < 640) qkvb[o] = (o < 64) ? qb[o] : (o < 128) ? kb[o - 64] : vb[o - 128];
  if (o < 512) {
    float s1 = g1[o] / sqrtf(v1[o] + 1e-5f);
    sc1[o] = s1; bi1[o] = b1[o] - m1[o] * s1;
    float s2 = g2[o] / sqrtf(v2[o] + 1e-5f);
    sc2[o] = s2; bi2[o] = b2[o] - m2[o] * s2;
  }
}

// x NCHW f32 -> xpad [4][66][66][2048] NHWC bf16 (interior; borders pre-zeroed by memset)
__global__ void pad_x(const float* __restrict__ x, bf16* __restrict__ xp) {
  __shared__ float tile[64][65];
  int bid = blockIdx.x;                  // 4*64*32
  int b = bid >> 11, h = (bid >> 5) & 63, cg = bid & 31;
  int tid = threadIdx.x;
  int wq = tid & 63, ci = tid >> 6;
#pragma unroll
  for (int r = 0; r < 16; ++r) {
    int cc = r * 4 + ci;
    tile[cc][wq] = x[(size_t)(b * 2048 + cg * 64 + cc) * 4096 + h * 64 + wq];
  }
  __syncthreads();
  int c2 = tid & 63, wi = tid >> 6;
#pragma unroll
  for (int r = 0; r < 16; ++r) {
    int w = r * 4 + wi;
    xp[((size_t)(b * 66 + h + 1) * 66 + (w + 1)) * 2048 + cg * 64 + c2] = (bf16)tile[c2][w];
  }
}

// ---------------------------------------------------------------- conv GEMM
// implicit GEMM: out[m=(b,h,w)][n] = sum_{tap,k} in[b, h+dy, w+dx, k] * wt[tap][n][k]
// in: padded NHWC bf16 [4][66][66][Kc].  OUT_F32=0: bf16 NHWC [4][64][64][512] feats
//                                        OUT_F32=1: f32 NCHW d_out, BN+ReLU both.
template <int OUT_F32>
__global__ __launch_bounds__(256, 2)
void conv_gemm(const bf16* __restrict__ in, int Kc, const bf16* __restrict__ wt,
               const float* __restrict__ sc, const float* __restrict__ bi,
               bf16* __restrict__ outb, float* __restrict__ outf) {
  __shared__ bf16 As[128 * 64];
  __shared__ bf16 Bs[128 * 64];
  const int bid = blockIdx.x;
  const int o = (bid & 7) * 64 + (bid >> 3);   // XCD swizzle (512 = 8*64)
  const int mt = o >> 2, nt = o & 3;
  const int p0 = mt * 128;
  const int b = p0 >> 12;
  const int h0 = (p0 >> 6) & 63;
  const int n0 = nt * 128;
  const int tid = threadIdx.x;

  const bf16* aSrc[4]; const bf16* bSrc[4];
  bf16* aDst[4]; bf16* bDst[4];
#pragma unroll
  for (int r = 0; r < 4; ++r) {
    const int u = r * 256 + tid;
    const int m = u >> 3, sp = u & 7;
    const int h = h0 + (m >> 6), w = m & 63;
    const int seg = (sp ^ (m & 7)) * 8;        // inverse-XOR-swizzled source
    aSrc[r] = in + (size_t)((b * 66 + h) * 66 + w) * Kc + seg;
    aDst[r] = As + u * 8;
    bSrc[r] = wt + (size_t)(n0 + m) * Kc + seg;
    bDst[r] = Bs + u * 8;
  }

  const int lane = tid & 63, wid = tid >> 6;
  const int lr = lane & 15, kg = lane >> 4;
  const int wm = (wid >> 1) * 64, wn = (wid & 1) * 64;

  int aoff[4][2], boff[4][2];
#pragma unroll
  for (int i = 0; i < 4; ++i)
#pragma unroll
    for (int kh = 0; kh < 2; ++kh) {
      const int ra = wm + i * 16 + lr;
      aoff[i][kh] = ra * 128 + ((kh * 64 + kg * 16) ^ ((ra & 7) << 4));
      const int rb = wn + i * 16 + lr;
      boff[i][kh] = rb * 128 + ((kh * 64 + kg * 16) ^ ((rb & 7) << 4));
    }

  f32x4 acc[4][4];
#pragma unroll
  for (int i = 0; i < 4; ++i)
#pragma unroll
    for (int j = 0; j < 4; ++j) acc[i][j] = f32x4{0.f, 0.f, 0.f, 0.f};

  const size_t wtap = (size_t)512 * Kc;
  for (int tap = 0; tap < 9; ++tap) {
    const int toff = ((tap / 3) * 66 + (tap % 3)) * Kc;
    const size_t wo = tap * wtap;
    for (int k0 = 0; k0 < Kc; k0 += 64) {
      __syncthreads();
#pragma unroll
      for (int r = 0; r < 4; ++r) gload16(aSrc[r] + toff + k0, aDst[r]);
#pragma unroll
      for (int r = 0; r < 4; ++r) gload16(bSrc[r] + wo + k0, bDst[r]);
      vmwait();
      __syncthreads();
#pragma unroll
      for (int kh = 0; kh < 2; ++kh) {
        bf16x8 av[4], bv[4];
#pragma unroll
        for (int i = 0; i < 4; ++i) av[i] = *(const bf16x8*)((const char*)As + aoff[i][kh]);
#pragma unroll
        for (int i = 0; i < 4; ++i) bv[i] = *(const bf16x8*)((const char*)Bs + boff[i][kh]);
#pragma unroll
        for (int mi = 0; mi < 4; ++mi)
#pragma unroll
          for (int ni = 0; ni < 4; ++ni)
            acc[mi][ni] = mfma16(av[mi], bv[ni], acc[mi][ni]);
      }
    }
  }

#pragma unroll
  for (int ni = 0; ni < 4; ++ni) {
    const int n = n0 + wn + ni * 16 + lr;
    const float scl = sc[n], bia = bi[n];
#pragma unroll
    for (int mi = 0; mi < 4; ++mi) {
      const int m = wm + mi * 16 + kg * 4;
      const int h = h0 + (m >> 6), w = m & 63;
      if (OUT_F32) {
        f32x4 st;
#pragma unroll
        for (int r = 0; r < 4; ++r) st[r] = fmaxf(acc[mi][ni][r] * scl + bia, 0.f);
        *(f32x4*)(outf + (size_t)(b * 512 + n) * 4096 + h * 64 + w) = st;
      } else {
#pragma unroll
        for (int r = 0; r < 4; ++r) {
          const float y = fmaxf(acc[mi][ni][r] * scl + bia, 0.f);
          outb[(size_t)((b * 64 + h) * 64 + w + r) * 512 + n] = (bf16)y;
        }
      }
    }
  }
}

// ---------------------------------------------------------------- q/k/v GEMM
// M=16384 pixels, N=640 (q:0-63, k:64-127, v:128-639), K=512.
__global__ __launch_bounds__(256, 2)
void qkv_gemm(const bf16* __restrict__ fin, int Ws, int off,
              const bf16* __restrict__ wq, const float* __restrict__ bias,
              bf16* __restrict__ q1, bf16* __restrict__ q2,
              bf16* __restrict__ k1, bf16* __restrict__ k2,
              bf16* __restrict__ vtc, bf16* __restrict__ vtr) {
  __shared__ bf16 As[128 * 64];
  __shared__ bf16 Bs[128 * 64];
  const int bid = blockIdx.x;
  const int o = (bid & 7) * 80 + (bid >> 3);   // 640 = 8*80
  const int mt = o / 5, nt = o % 5;
  const int p0 = mt * 128;
  const int b = p0 >> 12;
  const int h0 = (p0 >> 6) & 63;
  const int n0 = nt * 128;
  const int tid = threadIdx.x;

  const bf16* aSrc[4]; const bf16* bSrc[4];
  bf16* aDst[4]; bf16* bDst[4];
#pragma unroll
  for (int r = 0; r < 4; ++r) {
    const int u = r * 256 + tid;
    const int m = u >> 3, sp = u & 7;
    const int h = h0 + (m >> 6), w = m & 63;
    const int seg = (sp ^ (m & 7)) * 8;
    aSrc[r] = fin + (size_t)((b * Ws + h + off) * Ws + w + off) * 512 + seg;
    aDst[r] = As + u * 8;
    bSrc[r] = wq + (size_t)(n0 + m) * 512 + seg;
    bDst[r] = Bs + u * 8;
  }

  const int lane = tid & 63, wid = tid >> 6;
  const int lr = lane & 15, kg = lane >> 4;
  const int wm = (wid >> 1) * 64, wn = (wid & 1) * 64;

  int aoff[4][2], boff[4][2];
#pragma unroll
  for (int i = 0; i < 4; ++i)
#pragma unroll
    for (int kh = 0; kh < 2; ++kh) {
      const int ra = wm + i * 16 + lr;
      aoff[i][kh] = ra * 128 + ((kh * 64 + kg * 16) ^ ((ra & 7) << 4));
      const int rb = wn + i * 16 + lr;
      boff[i][kh] = rb * 128 + ((kh * 64 + kg * 16) ^ ((rb & 7) << 4));
    }

  f32x4 acc[4][4];
#pragma unroll
  for (int i = 0; i < 4; ++i)
#pragma unroll
    for (int j = 0; j < 4; ++j) acc[i][j] = f32x4{0.f, 0.f, 0.f, 0.f};

  for (int k0 = 0; k0 < 512; k0 += 64) {
    __syncthreads();
#pragma unroll
    for (int r = 0; r < 4; ++r) gload16(aSrc[r] + k0, aDst[r]);
#pragma unroll
    for (int r = 0; r < 4; ++r) gload16(bSrc[r] + k0, bDst[r]);
    vmwait();
    __syncthreads();
#pragma unroll
    for (int kh = 0; kh < 2; ++kh) {
      bf16x8 av[4], bv[4];
#pragma unroll
      for (int i = 0; i < 4; ++i) av[i] = *(const bf16x8*)((const char*)As + aoff[i][kh]);
#pragma unroll
      for (int i = 0; i < 4; ++i) bv[i] = *(const bf16x8*)((const char*)Bs + boff[i][kh]);
#pragma unroll
      for (int mi = 0; mi < 4; ++mi)
#pragma unroll
        for (int ni = 0; ni < 4; ++ni)
          acc[mi][ni] = mfma16(av[mi], bv[ni], acc[mi][ni]);
    }
  }

#pragma unroll
  for (int ni = 0; ni < 4; ++ni) {
    const int n = n0 + wn + ni * 16 + lr;
    const float bsv = bias[n];
#pragma unroll
    for (int mi = 0; mi < 4; ++mi) {
      const int m = wm + mi * 16 + kg * 4;
      const int h = h0 + (m >> 6);
#pragma unroll
      for (int r = 0; r < 4; ++r) {
        const int w = (m & 63) + r;
        const bf16 val = (bf16)(acc[mi][ni][r] + bsv);
        if (n < 64) {
          q1[(size_t)((b * 64 + h) * 64 + w) * 64 + n] = val;          // [b][h][w][o]
          q2[(size_t)((b * 64 + w) * 64 + h) * 64 + n] = val;          // [b][w][h][o]
        } else if (n < 128) {
          k1[(size_t)((b * 64 + h) * 64 + w) * 64 + (n - 64)] = val;
          k2[(size_t)((b * 64 + w) * 64 + h) * 64 + (n - 64)] = val;
        } else {
          const int c = n - 128;
          vtc[((size_t)(b * 64 + w) * 512 + c) * 64 + h] = val;        // [b][w][c][i=h]
          vtr[((size_t)(b * 64 + h) * 512 + c) * 64 + w] = val;        // [b][h][c][j=w]
        }
      }
    }
  }
}

// ---------------------------------------------------------------- attn logits
// block = (b, s): E[t][u] = sum_o q[s-slab][t][o] * k[s-slab][u][o];  e[bs][t][u] f32.
__global__ __launch_bounds__(256, 4)
void attn_logits(const bf16* __restrict__ q, const bf16* __restrict__ k,
                 float* __restrict__ e) {
  __shared__ bf16 Qs[64 * 64];
  __shared__ bf16 Ks[64 * 64];
  const int bs = blockIdx.x;
  const bf16* qs = q + (size_t)bs * 4096;
  const bf16* ks = k + (size_t)bs * 4096;
  const int tid = threadIdx.x;
#pragma unroll
  for (int r = 0; r < 2; ++r) {
    const int u = r * 256 + tid;
    const int row = u >> 3, sp = u & 7;
    const int seg = (sp ^ (row & 7)) * 8;
    gload16(qs + row * 64 + seg, Qs + u * 8);
    gload16(ks + row * 64 + seg, Ks + u * 8);
  }
  vmwait();
  __syncthreads();
  const int lane = tid & 63, wid = tid >> 6;
  const int lr = lane & 15, kg = lane >> 4;
  const int wm = wid * 16;
  f32x4 acc[4];
#pragma unroll
  for (int i = 0; i < 4; ++i) acc[i] = f32x4{0.f, 0.f, 0.f, 0.f};
#pragma unroll
  for (int kh = 0; kh < 2; ++kh) {
    const int ra = wm + lr;
    const bf16x8 av = *(const bf16x8*)((const char*)Qs + ra * 128 + ((kh * 64 + kg * 16) ^ ((ra & 7) << 4)));
#pragma unroll
    for (int ni = 0; ni < 4; ++ni) {
      const int rb = ni * 16 + lr;
      const bf16x8 bv = *(const bf16x8*)((const char*)Ks + rb * 128 + ((kh * 64 + kg * 16) ^ ((rb & 7) << 4)));
      acc[ni] = mfma16(av, bv, acc[ni]);
    }
  }
  float* eo = e + (size_t)bs * 4096;
#pragma unroll
  for (int ni = 0; ni < 4; ++ni)
#pragma unroll
    for (int r = 0; r < 4; ++r)
      eo[(wm + kg * 4 + r) * 64 + ni * 16 + lr] = acc[ni][r];
}

// ---------------------------------------------------------------- softmax (128-wide, eH diag masked)
__global__ __launch_bounds__(256)
void softmax_cca(const float* __restrict__ eH, const float* __restrict__ eW,
                 bf16* __restrict__ aH, bf16* __restrict__ aW) {
  const int lane = threadIdx.x & 63;
  const int p = blockIdx.x * 4 + (threadIdx.x >> 6);
  const int b = p >> 12, h = (p >> 6) & 63, w = p & 63;
  const size_t iH = ((size_t)(b * 64 + w) * 64 + h) * 64;
  const size_t iW = ((size_t)(b * 64 + h) * 64 + w) * 64;
  float vH = eH[iH + lane];
  if (lane == h) vH += -1.0e9f;
  const float vW = eW[iW + lane];
  float mx = fmaxf(vH, vW);
#pragma unroll
  for (int d = 32; d > 0; d >>= 1) mx = fmaxf(mx, __shfl_xor(mx, d));
  const float pH = __expf(vH - mx);
  const float pW = __expf(vW - mx);
  float sm = pH + pW;
#pragma unroll
  for (int d = 32; d > 0; d >>= 1) sm += __shfl_xor(sm, d);
  const float inv = 1.f / sm;
  aH[iH + lane] = (bf16)(pH * inv);
  aW[iW + lane] = (bf16)(pW * inv);
}

// ---------------------------------------------------------------- PV GEMM
// block = (b, s): Out[t][c] = sum_u attn[bs][t][u] * vt[bs][c][u]   (M=64,N=512,K=64)
// FINAL=0: colP[b][t][s][c] = Out (f32, NHWC with s=w, t=h)
// FINAL=1: fout = gamma*(colP[b][s][t][c] + Out) + fin   (s=h, t=w), bf16 NHWC(+pad)
template <int FINAL>
__global__ __launch_bounds__(256, 2)
void pv_gemm(const bf16* __restrict__ attn, const bf16* __restrict__ vt,
             float* __restrict__ colP,
             const bf16* __restrict__ fin, int WsI, int offI,
             bf16* __restrict__ fout, int WsO, int offO,
             const float* __restrict__ gptr) {
  __shared__ bf16 Ats[64 * 64];
  __shared__ bf16 Vs[256 * 64];
  const int bs = blockIdx.x;
  const int b = bs >> 6, s = bs & 63;
  const bf16* at = attn + (size_t)bs * 4096;
  const bf16* vs = vt + (size_t)bs * 32768;
  const int tid = threadIdx.x;
  const float gm = FINAL ? *gptr : 0.f;
#pragma unroll
  for (int r = 0; r < 2; ++r) {
    const int u = r * 256 + tid;
    const int row = u >> 3, sp = u & 7;
    gload16(at + row * 64 + (sp ^ (row & 7)) * 8, Ats + u * 8);
  }
  const int lane = tid & 63, wid = tid >> 6;
  const int lr = lane & 15, kg = lane >> 4;
  const int wnl = wid * 64;

  for (int ph = 0; ph < 2; ++ph) {
    __syncthreads();
#pragma unroll
    for (int r = 0; r < 8; ++r) {
      const int u = r * 256 + tid;
      const int row = u >> 3, sp = u & 7;
      gload16(vs + (size_t)(ph * 256 + row) * 64 + (sp ^ (row & 7)) * 8, Vs + u * 8);
    }
    vmwait();
    __syncthreads();
    f32x4 acc[4][4];
#pragma unroll
    for (int i = 0; i < 4; ++i)
#pragma unroll
      for (int j = 0; j < 4; ++j) acc[i][j] = f32x4{0.f, 0.f, 0.f, 0.f};
#pragma unroll
    for (int kh = 0; kh < 2; ++kh) {
      bf16x8 av[4];
#pragma unroll
      for (int i = 0; i < 4; ++i) {
        const int ra = i * 16 + lr;
        av[i] = *(const bf16x8*)((const char*)Ats + ra * 128 + ((kh * 64 + kg * 16) ^ ((ra & 7) << 4)));
      }
#pragma unroll
      for (int ni = 0; ni < 4; ++ni) {
        const int rb = wnl + ni * 16 + lr;
        const bf16x8 bv = *(const bf16x8*)((const char*)Vs + rb * 128 + ((kh * 64 + kg * 16) ^ ((rb & 7) << 4)));
#pragma unroll
        for (int mi = 0; mi < 4; ++mi)
          acc[mi][ni] = mfma16(av[mi], bv, acc[mi][ni]);
      }
    }
#pragma unroll
    for (int ni = 0; ni < 4; ++ni) {
      const int c = ph * 256 + wnl + ni * 16 + lr;
#pragma unroll
      for (int mi = 0; mi < 4; ++mi) {
        const int t0 = mi * 16 + kg * 4;
#pragma unroll
        for (int r = 0; r < 4; ++r) {
          const int t = t0 + r;
          if (!FINAL) {
            colP[((size_t)(b * 64 + t) * 64 + s) * 512 + c] = acc[mi][ni][r];
          } else {
            const float cp = colP[((size_t)(b * 64 + s) * 64 + t) * 512 + c];
            const float fi = (float)fin[(size_t)((b * WsI + s + offI) * WsI + t + offI) * 512 + c];
            fout[(size_t)((b * WsO + s + offO) * WsO + t + offO) * 512 + c] =
                (bf16)(gm * (cp + acc[mi][ni][r]) + fi);
          }
        }
      }
    }
  }
}

// ---------------------------------------------------------------- host launch

#define SZ_XPAD ((size_t)71368704)   // 4*66*66*2048*2
#define SZ_W1T  ((size_t)18874368)
#define SZ_W2T  ((size_t)4718592)
#define SZ_WQKV ((size_t)655360)
#define SZ_QKVB ((size_t)4096)
#define SZ_BN   ((size_t)8192)
#define SZ_F    ((size_t)16777216)   // 4*64*64*512*2
#define SZ_F3P  ((size_t)17842176)   // 4*66*66*512*2
#define SZ_Q    ((size_t)2097152)    // 4*64*64*64*2
#define SZ_COLP ((size_t)33554432)   // 4*64*64*512*4
#define SZ_E    ((size_t)4194304)    // 4*64*64*64*4

extern "C" void kernel_launch(void* const* d_in, const int* in_sizes, int n_in,
                              void* d_out, int out_size, void* d_ws, size_t ws_size,
                              hipStream_t stream) {
  const float* x  = (const float*)d_in[0];
  const float* w1 = (const float*)d_in[1];
  const float* g1 = (const float*)d_in[2];
  const float* b1 = (const float*)d_in[3];
  const float* m1 = (const float*)d_in[4];
  const float* v1 = (const float*)d_in[5];
  const float* qw = (const float*)d_in[6];
  const float* qb = (const float*)d_in[7];
  const float* kw = (const float*)d_in[8];
  const float* kb = (const float*)d_in[9];
  const float* vw = (const float*)d_in[10];
  const float* vb = (const float*)d_in[11];
  const float* gamma = (const float*)d_in[12];
  const float* w2 = (const float*)d_in[13];
  const float* g2 = (const float*)d_in[14];
  const float* b2 = (const float*)d_in[15];
  const float* m2 = (const float*)d_in[16];
  const float* v2 = (const float*)d_in[17];

  char* ws = (char*)d_ws;
  size_t off = 0;
  bf16* XPAD = (bf16*)(ws + off);        off += SZ_XPAD;
  bf16* W1T  = (bf16*)(ws + off);        off += SZ_W1T;
  bf16* W2T  = (bf16*)(ws + off);        off += SZ_W2T;
  bf16* WQKV = (bf16*)(ws + off);        off += SZ_WQKV;
  float* QKVB = (float*)(ws + off);      off += SZ_QKVB;
  float* SC1 = (float*)(ws + off);
  float* BI1 = (float*)(ws + off + 2048);
  float* SC2 = (float*)(ws + off + 4096);
  float* BI2 = (float*)(ws + off + 6144); off += SZ_BN;
  bf16* F1  = (bf16*)(ws + off);         off += SZ_F;
  bf16* F2  = (bf16*)(ws + off);         off += SZ_F;
  bf16* F3P = (bf16*)(ws + off);         off += SZ_F3P;
  bf16* Q1  = (bf16*)(ws + off);         off += SZ_Q;
  bf16* Q2  = (bf16*)(ws + off);         off += SZ_Q;
  bf16* K1  = (bf16*)(ws + off);         off += SZ_Q;
  bf16* K2  = (bf16*)(ws + off);         off += SZ_Q;
  bf16* VTC = (bf16*)(ws + off);         off += SZ_F;
  bf16* VTR = (bf16*)(ws + off);         off += SZ_F;
  bf16* AH  = (bf16*)(ws + off);         off += SZ_Q;
  bf16* AW  = (bf16*)(ws + off);         off += SZ_Q;
  // overlays on XPAD region (xpad dead after conv1)
  float* COLP = (float*)(ws + 0);
  float* EH   = (float*)(ws + SZ_COLP);
  float* EW   = (float*)(ws + SZ_COLP + SZ_E);

  hipMemsetAsync(XPAD, 0, SZ_XPAD, stream);
  hipMemsetAsync(F3P, 0, SZ_F3P, stream);

  prep_w<<<4096, 256, 0, stream>>>(w1, W1T, 512 * 2048);
  prep_w<<<1024, 256, 0, stream>>>(w2, W2T, 512 * 512);
  prep_misc<<<1280, 256, 0, stream>>>(qw, kw, vw, qb, kb, vb,
                                      g1, b1, m1, v1, g2, b2, m2, v2,
                                      WQKV, QKVB, SC1, BI1, SC2, BI2);
  pad_x<<<8192, 256, 0, stream>>>(x, XPAD);

  conv_gemm<0><<<512, 256, 0, stream>>>(XPAD, 2048, W1T, SC1, BI1, F1, nullptr);

  // CCA iteration 1: F1 -> F2
  qkv_gemm<<<640, 256, 0, stream>>>(F1, 64, 0, WQKV, QKVB, Q1, Q2, K1, K2, VTC, VTR);
  attn_logits<<<256, 256, 0, stream>>>(Q2, K2, EH);
  attn_logits<<<256, 256, 0, stream>>>(Q1, K1, EW);
  softmax_cca<<<4096, 256, 0, stream>>>(EH, EW, AH, AW);
  pv_gemm<0><<<256, 256, 0, stream>>>(AH, VTC, COLP, nullptr, 64, 0, nullptr, 64, 0, nullptr);
  pv_gemm<1><<<256, 256, 0, stream>>>(AW, VTR, COLP, F1, 64, 0, F2, 64, 0, gamma);

  // CCA iteration 2: F2 -> F3P (padded interior)
  qkv_gemm<<<640, 256, 0, stream>>>(F2, 64, 0, WQKV, QKVB, Q1, Q2, K1, K2, VTC, VTR);
  attn_logits<<<256, 256, 0, stream>>>(Q2, K2, EH);
  attn_logits<<<256, 256, 0, stream>>>(Q1, K1, EW);
  softmax_cca<<<4096, 256, 0, stream>>>(EH, EW, AH, AW);
  pv_gemm<0><<<256, 256, 0, stream>>>(AH, VTC, COLP, nullptr, 64, 0, nullptr, 64, 0, nullptr);
  pv_gemm<1><<<256, 256, 0, stream>>>(AW, VTR, COLP, F2, 64, 0, F3P, 66, 1, gamma);

  conv_gemm<1><<<512, 256, 0, stream>>>(F3P, 512, W2T, SC2, BI2, nullptr, (float*)d_out);
}